// Round 3
// baseline (1176.012 us; speedup 1.0000x reference)
//
#include <hip/hip_runtime.h>

// ---------------- problem constants ----------------
#define NUM_GRAPHS 64
#define NODE_SZ    200
#define FEAT       200
#define HID        256
#define HALF       128
#define N_NODES    (NUM_GRAPHS * NODE_SZ)   // 12800
#define KREAD      (NODE_SZ * HID)          // 51200
#define NBLK       256
#define NTHR       512

typedef unsigned short ushort_t;
typedef unsigned int uint_t;
typedef __attribute__((ext_vector_type(8))) short bf16x8;
typedef __attribute__((ext_vector_type(4))) float f32x4;

#define GAS(p) ((const __attribute__((address_space(1))) void*)(p))
#define LAS(p) ((__attribute__((address_space(3))) void*)(p))

__device__ __forceinline__ float bf2f(ushort_t u) {
    union { unsigned int i; float f; } v; v.i = ((unsigned int)u) << 16; return v.f;
}
__device__ __forceinline__ ushort_t f2bf(float f) {
    union { float f; unsigned int i; } v; v.f = f;
    unsigned int x = v.i;
    unsigned int r = (x + 0x7fffu + ((x >> 16) & 1u)) >> 16;  // RNE
    return (ushort_t)r;
}

// ---------------- hand-rolled grid barrier (poison-proof: flags zeroed by init kernel) ----
__device__ __forceinline__ void gbar(uint_t* __restrict__ flags, int k) {
    __threadfence();                       // release: flush this thread's prior writes (agent)
    __syncthreads();                       // all block threads' fences done before signal
    if (threadIdx.x == 0)
        __hip_atomic_store(&flags[(k << 8) | blockIdx.x], 1u,
                           __ATOMIC_RELAXED, __HIP_MEMORY_SCOPE_AGENT);
    if (threadIdx.x < NBLK) {
        int cap = 0;
        while (__hip_atomic_load(&flags[(k << 8) | threadIdx.x],
                                 __ATOMIC_RELAXED, __HIP_MEMORY_SCOPE_AGENT) == 0u) {
            __builtin_amdgcn_s_sleep(2);
            if (++cap > (1 << 18)) break;  // safety valve: wrong-but-terminating on residency fail
        }
    }
    __syncthreads();
    __threadfence();                       // acquire: invalidate so fresh data is read
}

// ---------------- phase: per-layer GEMM  Y = A @ W^T ----------------
// tile 128M x 256N, BK=32, 8 waves = (4 M-waves of 32) x (2 N-waves of 128). 200 tiles.
__device__ __forceinline__ void gemm_phase(const ushort_t* __restrict__ A,
                                           const ushort_t* __restrict__ Bw,
                                           ushort_t* __restrict__ Y,
                                           ushort_t* smem) {
    int t = blockIdx.x;
    if (t >= 200) return;
    int mBase = (t >> 1) * 128;
    int nBase = (t & 1) * 256;
    int tid  = threadIdx.x;
    int lane = tid & 63;
    int wv   = tid >> 6;
    int r    = lane & 15;
    int quad = lane >> 4;
    int wm   = wv >> 1;        // 0..3 : M 32-block
    int wn   = wv & 1;         // 0..1 : N 128-block

    int rowA = tid >> 2, colc = (tid & 3) * 8;
    const ushort_t* gA  = A  + (size_t)(mBase + rowA) * 256 + colc;
    const ushort_t* gB0 = Bw + (size_t)(nBase + rowA) * 256 + colc;
    const ushort_t* gB1 = Bw + (size_t)(nBase + 128 + rowA) * 256 + colc;

    f32x4 acc[2][8];
#pragma unroll
    for (int i = 0; i < 2; ++i)
#pragma unroll
        for (int j = 0; j < 8; ++j) acc[i][j] = (f32x4){0.f, 0.f, 0.f, 0.f};

    // LDS: As dbuf at ushort idx 0 / 4096, Bs dbuf at 8192 / 16384. total 48 KB.
    auto STAGE = [&](int buf, int kb) {
        ushort_t* Ad = smem + (buf << 12) + tid * 8;
        ushort_t* Bd = smem + 8192 + (buf << 13) + tid * 8;
        __builtin_amdgcn_global_load_lds(GAS(gA + kb), LAS(Ad), 16, 0, 0);
        __builtin_amdgcn_global_load_lds(GAS(gB0 + kb), LAS(Bd), 16, 0, 0);
        __builtin_amdgcn_global_load_lds(GAS(gB1 + kb), LAS(Bd + 4096), 16, 0, 0);
    };

    STAGE(0, 0);
    for (int kt = 0; kt < 8; ++kt) {
        int cb = kt & 1;
        __syncthreads();
        if (kt < 7) STAGE(cb ^ 1, (kt + 1) * 32);
        const ushort_t* Ac = smem + (cb << 12);
        const ushort_t* Bc = smem + 8192 + (cb << 13);
        bf16x8 af[2];
#pragma unroll
        for (int i = 0; i < 2; ++i)
            af[i] = *(const bf16x8*)&Ac[(wm * 32 + i * 16 + r) * 32 + quad * 8];
#pragma unroll
        for (int j = 0; j < 8; ++j) {
            bf16x8 bfr = *(const bf16x8*)&Bc[(wn * 128 + j * 16 + r) * 32 + quad * 8];
            acc[0][j] = __builtin_amdgcn_mfma_f32_16x16x32_bf16(af[0], bfr, acc[0][j], 0, 0, 0);
            acc[1][j] = __builtin_amdgcn_mfma_f32_16x16x32_bf16(af[1], bfr, acc[1][j], 0, 0, 0);
        }
    }
#pragma unroll
    for (int i = 0; i < 2; ++i)
#pragma unroll
        for (int j = 0; j < 8; ++j) {
            int c = nBase + wn * 128 + j * 16 + r;
#pragma unroll
            for (int reg = 0; reg < 4; ++reg) {
                int m = mBase + wm * 32 + i * 16 + quad * 4 + reg;
                Y[(size_t)m * 512 + c] = f2bf(acc[i][j][reg]);
            }
        }
}

// ---------------- phase: aggregate projected rows + combine ----------------
__device__ __forceinline__ void agg_phase(const ushort_t* __restrict__ Y,
                                          const uint2* __restrict__ obnd,
                                          const uint2* __restrict__ es,
                                          const float* __restrict__ bp,
                                          const float* __restrict__ bn,
                                          ushort_t* __restrict__ outp, bool leaky) {
    int lane = threadIdx.x & 63;
    int c0 = lane * 2;
    int nw = gridDim.x << 3;
    for (int n = (blockIdx.x << 3) + (threadIdx.x >> 6); n < N_NODES; n += nw) {
        uint2 ob = obnd[n];
        uint_t off = ob.x, mid = ob.y, end = obnd[n + 1].x;
        float accp[2] = {0.f, 0.f};
        float accn[2] = {0.f, 0.f};
#pragma unroll 1
        for (int phase = 0; phase < 2; ++phase) {
            uint_t lo = phase ? mid : off;
            uint_t hi = phase ? end : mid;
            float* acc = phase ? accn : accp;
            const ushort_t* Yb = Y + (phase ? 128 : 0) + c0;
#pragma unroll 1
            for (uint_t base = lo; base < hi; base += 64) {
                int cnt = (int)min(64u, hi - base);
                uint2 rec = es[base + (uint_t)min(lane, cnt - 1)];
                int i = 0;
#pragma unroll 1
                for (; i + 8 <= cnt; i += 8) {
                    int s[8]; float w[8]; uint_t u[8];
#pragma unroll
                    for (int j = 0; j < 8; ++j) {
                        s[j] = __shfl((int)rec.x, i + j);
                        w[j] = __uint_as_float((uint_t)__shfl((int)rec.y, i + j));
                    }
#pragma unroll
                    for (int j = 0; j < 8; ++j) u[j] = *(const uint_t*)&Yb[(size_t)s[j] * 512];
#pragma unroll
                    for (int j = 0; j < 8; ++j) {
                        acc[0] = fmaf(w[j], bf2f((ushort_t)(u[j] & 0xffffu)), acc[0]);
                        acc[1] = fmaf(w[j], bf2f((ushort_t)(u[j] >> 16)), acc[1]);
                    }
                }
#pragma unroll 1
                for (; i < cnt; ++i) {
                    int s = __shfl((int)rec.x, i);
                    float w = __uint_as_float((uint_t)__shfl((int)rec.y, i));
                    uint_t u = *(const uint_t*)&Yb[(size_t)s * 512];
                    acc[0] = fmaf(w, bf2f((ushort_t)(u & 0xffffu)), acc[0]);
                    acc[1] = fmaf(w, bf2f((ushort_t)(u >> 16)), acc[1]);
                }
            }
        }
        float dp = fmaxf((float)(mid - off), 1.0f);
        float dn = fmaxf((float)(end - mid), 1.0f);
        float rp = 1.0f / dp, rn = 1.0f / dn;
        uint_t zp = *(const uint_t*)&Y[(size_t)n * 512 + 256 + c0];
        uint_t zn = *(const uint_t*)&Y[(size_t)n * 512 + 384 + c0];
        float vp0 = fmaf(accp[0], rp, bf2f((ushort_t)(zp & 0xffffu)) + bp[c0]);
        float vp1 = fmaf(accp[1], rp, bf2f((ushort_t)(zp >> 16))     + bp[c0 + 1]);
        float vn0 = fmaf(accn[0], rn, bf2f((ushort_t)(zn & 0xffffu)) + bn[c0]);
        float vn1 = fmaf(accn[1], rn, bf2f((ushort_t)(zn >> 16))     + bn[c0 + 1]);
        if (leaky) {
            vp0 = (vp0 > 0.0f) ? vp0 : 0.01f * vp0;
            vp1 = (vp1 > 0.0f) ? vp1 : 0.01f * vp1;
            vn0 = (vn0 > 0.0f) ? vn0 : 0.01f * vn0;
            vn1 = (vn1 > 0.0f) ? vn1 : 0.01f * vn1;
        }
        uint_t op = (uint_t)f2bf(vp0) | ((uint_t)f2bf(vp1) << 16);
        uint_t on = (uint_t)f2bf(vn0) | ((uint_t)f2bf(vn1) << 16);
        *(uint_t*)&outp[(size_t)n * 256 + c0]       = op;
        *(uint_t*)&outp[(size_t)n * 256 + 128 + c0] = on;
    }
}

// ---------------- phase: readout (split-K, 256 tiles = 1/block) ----------------
__device__ __forceinline__ void readout_phase(const ushort_t* __restrict__ h,
                                              const float* __restrict__ Wr,
                                              float* __restrict__ partial,
                                              ushort_t* smem) {
    ushort_t* As = smem;           // 64 x 32
    ushort_t* Bs = smem + 2048;    // 64 x 32
    int b = blockIdx.x;
    int nBase  = (b & 3) * 64;
    int kStart = (b >> 2) * 800;
    int tid  = threadIdx.x;
    int lane = tid & 63;
    int wv   = tid >> 6;
    int r    = lane & 15;
    int quad = lane >> 4;
    int wm   = wv >> 1;            // 0..3 : graphs 16-block
    int wn   = wv & 1;             // 0..1 : cols 32-block

    f32x4 acc[2];
    acc[0] = (f32x4){0.f, 0.f, 0.f, 0.f};
    acc[1] = (f32x4){0.f, 0.f, 0.f, 0.f};

    for (int kt = 0; kt < 25; ++kt) {
        int kBase = kStart + kt * 32;
        if (tid < 256) {
            int lin = tid * 8;
            int row = lin >> 5, col = lin & 31;
            *(uint4*)&As[lin] = *(const uint4*)&h[(size_t)row * KREAD + kBase + col];
            const float* wp = &Wr[(size_t)(nBase + row) * KREAD + kBase + col];
            float4 f0 = *(const float4*)&wp[0];
            float4 f1 = *(const float4*)&wp[4];
            ushort4 b0, b1;
            b0.x = f2bf(f0.x); b0.y = f2bf(f0.y); b0.z = f2bf(f0.z); b0.w = f2bf(f0.w);
            b1.x = f2bf(f1.x); b1.y = f2bf(f1.y); b1.z = f2bf(f1.z); b1.w = f2bf(f1.w);
            *(ushort4*)&Bs[lin]     = b0;
            *(ushort4*)&Bs[lin + 4] = b1;
        }
        __syncthreads();
        bf16x8 a = *(const bf16x8*)&As[(wm * 16 + r) * 32 + quad * 8];
#pragma unroll
        for (int j = 0; j < 2; ++j) {
            bf16x8 bb = *(const bf16x8*)&Bs[(wn * 32 + j * 16 + r) * 32 + quad * 8];
            acc[j] = __builtin_amdgcn_mfma_f32_16x16x32_bf16(a, bb, acc[j], 0, 0, 0);
        }
        __syncthreads();
    }
    float* o = partial + (size_t)(b >> 2) * (64 * HID);
#pragma unroll
    for (int j = 0; j < 2; ++j) {
        int c = nBase + wn * 32 + j * 16 + r;
#pragma unroll
        for (int reg = 0; reg < 4; ++reg) {
            int g = wm * 16 + quad * 4 + reg;
            o[g * HID + c] = acc[j][reg];
        }
    }
}

// ---------------- phase: final fold ----------------
__device__ __forceinline__ void final_phase(const float* __restrict__ partial,
                                            const float* __restrict__ br,
                                            const float* __restrict__ Wl,
                                            const float* __restrict__ bl,
                                            float* __restrict__ out, float* shf) {
    int g = blockIdx.x;
    if (g >= NUM_GRAPHS) return;
    int tid = threadIdx.x;
    if (tid < 256) {
        int c = tid;
        float s = 0.0f;
#pragma unroll 4
        for (int k = 0; k < 64; ++k) s += partial[(size_t)k * (64 * HID) + g * HID + c];
        float v = (s + br[c]) * Wl[c];
#pragma unroll
        for (int d = 32; d > 0; d >>= 1) v += __shfl_down(v, d);
        if ((c & 63) == 0) shf[c >> 6] = v;
    }
    __syncthreads();
    if (tid == 0) out[g] = shf[0] + shf[1] + shf[2] + shf[3] + bl[0];
}

// ---------------- init kernel: zero barrier flags + counters (every replay) ----------------
__global__ __launch_bounds__(512) void init_kernel(uint_t* __restrict__ flags,
                                                   uint_t* __restrict__ cnt,
                                                   uint_t* __restrict__ cur) {
    int i = blockIdx.x * 512 + threadIdx.x;
    int GS = gridDim.x * 512;
    for (int k = i; k < 16 * NBLK; k += GS) flags[k] = 0u;
    for (int k = i; k < N_NODES; k += GS) { cnt[k] = 0u; cur[k] = 0u; }
}

// ---------------- the mega-kernel ----------------
__global__ __launch_bounds__(NTHR, 2) void mega_kernel(
        const float* __restrict__ x, const int* __restrict__ ei, const float* __restrict__ ew,
        const float* __restrict__ Wp0, const float* __restrict__ Wn0,
        const float* __restrict__ Wp1, const float* __restrict__ Wn1,
        const float* __restrict__ Wp2, const float* __restrict__ Wn2,
        const float* __restrict__ bp0, const float* __restrict__ bn0,
        const float* __restrict__ bp1, const float* __restrict__ bn1,
        const float* __restrict__ bp2, const float* __restrict__ bn2,
        const float* __restrict__ Wr, const float* __restrict__ br,
        const float* __restrict__ Wl, const float* __restrict__ bl,
        float* __restrict__ out, char* __restrict__ ws, int E) {
    // ---- workspace carve (bytes) ----
    float*    partial = (float*)(ws);                   // 4,194,304
    uint_t*   cnt     = (uint_t*)(ws + 4194304);        // 51,200
    uint_t*   cur     = (uint_t*)(ws + 4245504);        // 51,200
    uint_t*   pref    = (uint_t*)(ws + 4296704);        // 51,200
    uint_t*   bsum    = (uint_t*)(ws + 4347904);        // 1,024 (+pad)
    uint2*    obnd    = (uint2*)(ws + 4349952);         // 12801*8
    uint2*    es      = (uint2*)(ws + 4452416);         // E*8 = 3,276,800
    ushort_t* Yall    = (ushort_t*)(ws + 7729216);      // 12800*512*2
    ushort_t* hA      = (ushort_t*)(ws + 20836416);     // 12800*256*2
    ushort_t* hB      = (ushort_t*)(ws + 27390016);     // 12800*256*2
    ushort_t* wall    = (ushort_t*)(ws + 33943616);     // 3*512*256*2
    ushort_t* xb      = (ushort_t*)(ws + 34730048);     // 12800*256*2 -> 41,283,648
    uint_t*   flags   = (uint_t*)(ws + 41283648);       // 16*256*4 -> 41,300,032

    __shared__ __align__(16) ushort_t smem[24576];      // 48 KB, reused across phases

    int tid = threadIdx.x;
    int gid = blockIdx.x * NTHR + tid;
    const int GSZ = NBLK * NTHR;                        // 131072

    // ---- S0: weight rearrange/cast + x cast/pad + degree histogram (cnt pre-zeroed) ----
    for (int idx = gid; idx < 3 * 131072; idx += GSZ) {
        int layer = idx >> 17, within = idx & 131071;
        int rr = within >> 8, col = within & 255;
        const float* Wp = (layer == 0) ? Wp0 : (layer == 1) ? Wp1 : Wp2;
        const float* Wn = (layer == 0) ? Wn0 : (layer == 1) ? Wn1 : Wn2;
        int Ks = (layer == 0) ? 200 : 256;
        int q = rr >> 7;                                // 0:Pl 1:Nl 2:Pr 3:Nr
        const float* Wsrc = (q & 1) ? Wn : Wp;
        int row = rr & 127;
        int scol = col + ((q >> 1) ? Ks : 0);
        float v = (col < Ks) ? Wsrc[(size_t)row * (2 * Ks) + scol] : 0.0f;
        wall[idx] = f2bf(v);
    }
    for (int idx = gid; idx < N_NODES * 64; idx += GSZ) {
        int n = idx >> 6, c0 = (idx & 63) * 4;
        ushort4 o = {0, 0, 0, 0};
        if (c0 < 200) {
            float4 v = *(const float4*)&x[(size_t)n * 200 + c0];
            o.x = f2bf(v.x); o.y = f2bf(v.y); o.z = f2bf(v.z); o.w = f2bf(v.w);
        }
        *(ushort4*)&xb[(size_t)n * 256 + c0] = o;
    }
    for (int e = gid; e < E; e += GSZ) {
        int dst = ei[E + e];
        float w = ew[e];
        if (w > 0.0f)      atomicAdd(&cnt[dst], 1u);
        else if (w < 0.0f) atomicAdd(&cnt[dst], 0x10000u);
    }
    gbar(flags, 0);

    // ---- S1: block-local exclusive scan (50 nodes/block, wave 0) ----
    if (tid < 64) {
        int b = blockIdx.x, lane = tid;
        int n = b * 50 + lane;
        uint_t c = (lane < 50) ? cnt[n] : 0u;
        uint_t tot = (c & 0xffffu) + (c >> 16);
        uint_t inc = tot;
#pragma unroll
        for (int d = 1; d < 64; d <<= 1) {
            uint_t up = (uint_t)__shfl_up((int)inc, d);
            if (lane >= d) inc += up;
        }
        if (lane < 50) pref[n] = inc - tot;
        if (lane == 63) bsum[b] = inc;
    }
    gbar(flags, 1);

    // ---- S2: cross-block offsets + write obnd ----
    if (tid < 64) {
        int b = blockIdx.x, lane = tid;
        uint_t sB = 0, sA = 0;
#pragma unroll
        for (int j0 = 0; j0 < 256; j0 += 64) {
            uint_t v = bsum[j0 + lane];
            sA += v;
            if (j0 + lane < b) sB += v;
        }
#pragma unroll
        for (int d = 32; d > 0; d >>= 1) {
            sB += (uint_t)__shfl_xor((int)sB, d);
            sA += (uint_t)__shfl_xor((int)sA, d);
        }
        if (lane < 50) {
            int n = b * 50 + lane;
            uint_t off = sB + pref[n];
            uint_t pc = cnt[n] & 0xffffu;
            obnd[n] = make_uint2(off, off + pc);
        }
        if (b == 0 && lane == 0) obnd[N_NODES] = make_uint2(sA, sA);
    }
    gbar(flags, 2);

    // ---- S3: scatter edges into CSR slots + GEMM layer 0 (independent work) ----
    for (int e = gid; e < E; e += GSZ) {
        int src = ei[e];
        int dst = ei[E + e];
        float w = ew[e];
        if (w > 0.0f) {
            uint_t old = atomicAdd(&cur[dst], 1u);
            es[obnd[dst].x + (old & 0xffffu)] = make_uint2((uint_t)src, __float_as_uint(w));
        } else if (w < 0.0f) {
            uint_t old = atomicAdd(&cur[dst], 0x10000u);
            es[obnd[dst].y + (old >> 16)] = make_uint2((uint_t)src, __float_as_uint(-w));
        }
    }
    gemm_phase(xb, wall, Yall, smem);
    gbar(flags, 3);

    // ---- S4..S8: agg0, (gemm,agg) x2 ----
    agg_phase(Yall, obnd, es, bp0, bn0, hA, true);
    gbar(flags, 4);
    gemm_phase(hA, wall + 131072, Yall, smem);
    gbar(flags, 5);
    agg_phase(Yall, obnd, es, bp1, bn1, hB, true);
    gbar(flags, 6);
    gemm_phase(hB, wall + 262144, Yall, smem);
    gbar(flags, 7);
    agg_phase(Yall, obnd, es, bp2, bn2, hA, false);
    gbar(flags, 8);

    // ---- S9: readout ----
    readout_phase(hA, Wr, partial, smem);
    gbar(flags, 9);

    // ---- S10: final ----
    final_phase(partial, br, Wl, bl, out, (float*)smem);
}

// ---------------- launch ----------------
extern "C" void kernel_launch(void* const* d_in, const int* in_sizes, int n_in,
                              void* d_out, int out_size, void* d_ws, size_t ws_size,
                              hipStream_t stream) {
    const float* x  = (const float*)d_in[0];
    const int*   ei = (const int*)d_in[1];
    const float* ew = (const float*)d_in[2];
    const float* Wp0 = (const float*)d_in[4];
    const float* bp0 = (const float*)d_in[5];
    const float* Wn0 = (const float*)d_in[6];
    const float* bn0 = (const float*)d_in[7];
    const float* Wp1 = (const float*)d_in[8];
    const float* bp1 = (const float*)d_in[9];
    const float* Wn1 = (const float*)d_in[10];
    const float* bn1 = (const float*)d_in[11];
    const float* Wp2 = (const float*)d_in[12];
    const float* bp2 = (const float*)d_in[13];
    const float* Wn2 = (const float*)d_in[14];
    const float* bn2 = (const float*)d_in[15];
    const float* Wr  = (const float*)d_in[16];
    const float* br  = (const float*)d_in[17];
    const float* Wl  = (const float*)d_in[18];
    const float* bl  = (const float*)d_in[19];
    int E = in_sizes[1] / 2;   // 409600

    char* ws = (char*)d_ws;
    uint_t* flags = (uint_t*)(ws + 41283648);
    uint_t* cnt   = (uint_t*)(ws + 4194304);
    uint_t* cur   = (uint_t*)(ws + 4245504);

    hipLaunchKernelGGL(init_kernel, dim3(64), dim3(512), 0, stream, flags, cnt, cur);
    hipLaunchKernelGGL(mega_kernel, dim3(NBLK), dim3(NTHR), 0, stream,
                       x, ei, ew,
                       Wp0, Wn0, Wp1, Wn1, Wp2, Wn2,
                       bp0, bn0, bp1, bn1, bp2, bn2,
                       Wr, br, Wl, bl,
                       (float*)d_out, ws, E);
}

// Round 4
// 303.669 us; speedup vs baseline: 3.8727x; 3.8727x over previous
//
#include <hip/hip_runtime.h>

// ---------------- problem constants ----------------
#define NUM_GRAPHS 64
#define NODE_SZ    200
#define FEAT       200
#define HID        256
#define HALF       128
#define N_NODES    (NUM_GRAPHS * NODE_SZ)   // 12800
#define KREAD      (NODE_SZ * HID)          // 51200

typedef unsigned short ushort_t;
typedef unsigned int uint_t;
typedef __attribute__((ext_vector_type(8))) short bf16x8;
typedef __attribute__((ext_vector_type(4))) float f32x4;

#define GAS(p) ((const __attribute__((address_space(1))) void*)(p))
#define LAS(p) ((__attribute__((address_space(3))) void*)(p))

__device__ __forceinline__ float bf2f(ushort_t u) {
    union { unsigned int i; float f; } v; v.i = ((unsigned int)u) << 16; return v.f;
}
__device__ __forceinline__ ushort_t f2bf(float f) {
    union { float f; unsigned int i; } v; v.f = f;
    unsigned int x = v.i;
    unsigned int r = (x + 0x7fffu + ((x >> 16) & 1u)) >> 16;  // RNE
    return (ushort_t)r;
}

// ---------------- K1: zero counters + weight rearrange/cast + x cast/pad ----------------
// Weight layout per layer (wall, [512 x 256] bf16):
//   rows   0..127 : Wp[:, :K] | 128..255 : Wn[:, :K] | 256..383 : Wp[:, K:2K] | 384..511 : Wn[:, K:2K]
// K=200 for layer 0 (cols 200..255 zero), K=256 for layers 1,2.
__global__ __launch_bounds__(256) void prep_kernel(
        const float* __restrict__ Wp0, const float* __restrict__ Wn0,
        const float* __restrict__ Wp1, const float* __restrict__ Wn1,
        const float* __restrict__ Wp2, const float* __restrict__ Wn2,
        const float* __restrict__ x,
        uint_t* __restrict__ cntcur, ushort_t* __restrict__ wall,
        ushort_t* __restrict__ xb) {
    int gid = blockIdx.x * 256 + threadIdx.x;
    const int GS = gridDim.x * 256;
    for (int i = gid; i < 2 * N_NODES; i += GS) cntcur[i] = 0u;
    for (int idx = gid; idx < 3 * 131072; idx += GS) {
        int layer = idx >> 17, within = idx & 131071;
        int rr = within >> 8, col = within & 255;
        const float* Wp = (layer == 0) ? Wp0 : (layer == 1) ? Wp1 : Wp2;
        const float* Wn = (layer == 0) ? Wn0 : (layer == 1) ? Wn1 : Wn2;
        int Ks = (layer == 0) ? 200 : 256;
        int q = rr >> 7;                                 // 0:Pl 1:Nl 2:Pr 3:Nr
        const float* Wsrc = (q & 1) ? Wn : Wp;
        int row = rr & 127;
        int scol = col + ((q >> 1) ? Ks : 0);
        float v = (col < Ks) ? Wsrc[(size_t)row * (2 * Ks) + scol] : 0.0f;
        wall[idx] = f2bf(v);
    }
    for (int idx = gid; idx < N_NODES * 64; idx += GS) {
        int n = idx >> 6, c0 = (idx & 63) * 4;
        ushort4 o = {0, 0, 0, 0};
        if (c0 < 200) {
            float4 v = *(const float4*)&x[(size_t)n * 200 + c0];
            o.x = f2bf(v.x); o.y = f2bf(v.y); o.z = f2bf(v.z); o.w = f2bf(v.w);
        }
        *(ushort4*)&xb[(size_t)n * 256 + c0] = o;
    }
}

// ---------------- K2: degree histogram (pos lo16 / neg hi16), global atomics ----------------
__global__ __launch_bounds__(512) void hist_kernel(const int* __restrict__ ei,
                                                   const float* __restrict__ ew,
                                                   uint_t* __restrict__ cnt, int E) {
    int e = blockIdx.x * 512 + threadIdx.x;
    if (e < E) {
        int dst = ei[E + e];
        float w = ew[e];
        if (w > 0.0f)      atomicAdd(&cnt[dst], 1u);
        else if (w < 0.0f) atomicAdd(&cnt[dst], 0x10000u);
    }
}

// ---------------- K3: exclusive scan over packed counts -> obnd ----------------
__global__ __launch_bounds__(1024) void scan_kernel(const uint_t* __restrict__ cnt,
                                                    uint2* __restrict__ obnd, int n) {
    const int PER = 13;
    int t = threadIdx.x;
    int start = t * PER;
    int local[PER];
    uint_t pcnt[PER];
    int sum = 0;
#pragma unroll
    for (int i = 0; i < PER; ++i) {
        int idx = start + i;
        uint_t c = (idx < n) ? cnt[idx] : 0u;
        int v = (int)((c & 0xffffu) + (c >> 16));
        pcnt[i] = c & 0xffffu;
        local[i] = sum;
        sum += v;
    }
    int lane = t & 63, wid = t >> 6;
    int inc = sum;
#pragma unroll
    for (int d = 1; d < 64; d <<= 1) {
        int up = __shfl_up(inc, d);
        if (lane >= d) inc += up;
    }
    __shared__ int wsum[16], woff[16];
    if (lane == 63) wsum[wid] = inc;
    __syncthreads();
    if (t < 16) {
        int acc = 0;
        for (int j = 0; j < 16; ++j) if (j < t) acc += wsum[j];
        woff[t] = acc;
    }
    __syncthreads();
    int base = woff[wid] + (inc - sum);
#pragma unroll
    for (int i = 0; i < PER; ++i) {
        int idx = start + i;
        if (idx < n) {
            uint_t off = (uint_t)(base + local[i]);
            obnd[idx] = make_uint2(off, off + pcnt[i]);
        }
    }
    if (t == 1023) {
        uint_t tot = (uint_t)(base + sum);
        obnd[n] = make_uint2(tot, tot);
    }
}

// ---------------- GEMM phase body: Y = A @ W^T, tile 128M x 256N, 8 waves, BK=32 ----------------
__device__ __forceinline__ void gemm_body(int t, const ushort_t* __restrict__ A,
                                          const ushort_t* __restrict__ Bw,
                                          ushort_t* __restrict__ Y,
                                          ushort_t* smem) {
    int mBase = (t >> 1) * 128;
    int nBase = (t & 1) * 256;
    int tid  = threadIdx.x;
    int lane = tid & 63;
    int wv   = tid >> 6;
    int r    = lane & 15;
    int quad = lane >> 4;
    int wm   = wv >> 1;        // 0..3 : M 32-block
    int wn   = wv & 1;         // 0..1 : N 128-block

    int rowA = tid >> 2, colc = (tid & 3) * 8;
    const ushort_t* gA  = A  + (size_t)(mBase + rowA) * 256 + colc;
    const ushort_t* gB0 = Bw + (size_t)(nBase + rowA) * 256 + colc;
    const ushort_t* gB1 = Bw + (size_t)(nBase + 128 + rowA) * 256 + colc;

    f32x4 acc[2][8];
#pragma unroll
    for (int i = 0; i < 2; ++i)
#pragma unroll
        for (int j = 0; j < 8; ++j) acc[i][j] = (f32x4){0.f, 0.f, 0.f, 0.f};

    // LDS: As dbuf at ushort idx 0 / 4096, Bs dbuf at 8192 / 16384. total 48 KB.
    auto STAGE = [&](int buf, int kb) {
        ushort_t* Ad = smem + (buf << 12) + tid * 8;
        ushort_t* Bd = smem + 8192 + (buf << 13) + tid * 8;
        __builtin_amdgcn_global_load_lds(GAS(gA + kb), LAS(Ad), 16, 0, 0);
        __builtin_amdgcn_global_load_lds(GAS(gB0 + kb), LAS(Bd), 16, 0, 0);
        __builtin_amdgcn_global_load_lds(GAS(gB1 + kb), LAS(Bd + 4096), 16, 0, 0);
    };

    STAGE(0, 0);
    for (int kt = 0; kt < 8; ++kt) {
        int cb = kt & 1;
        __syncthreads();
        if (kt < 7) STAGE(cb ^ 1, (kt + 1) * 32);
        const ushort_t* Ac = smem + (cb << 12);
        const ushort_t* Bc = smem + 8192 + (cb << 13);
        bf16x8 af[2];
#pragma unroll
        for (int i = 0; i < 2; ++i)
            af[i] = *(const bf16x8*)&Ac[(wm * 32 + i * 16 + r) * 32 + quad * 8];
#pragma unroll
        for (int j = 0; j < 8; ++j) {
            bf16x8 bfr = *(const bf16x8*)&Bc[(wn * 128 + j * 16 + r) * 32 + quad * 8];
            acc[0][j] = __builtin_amdgcn_mfma_f32_16x16x32_bf16(af[0], bfr, acc[0][j], 0, 0, 0);
            acc[1][j] = __builtin_amdgcn_mfma_f32_16x16x32_bf16(af[1], bfr, acc[1][j], 0, 0, 0);
        }
    }
#pragma unroll
    for (int i = 0; i < 2; ++i)
#pragma unroll
        for (int j = 0; j < 8; ++j) {
            int c = nBase + wn * 128 + j * 16 + r;
#pragma unroll
            for (int reg = 0; reg < 4; ++reg) {
                int m = mBase + wm * 32 + i * 16 + quad * 4 + reg;
                Y[(size_t)m * 512 + c] = f2bf(acc[i][j][reg]);
            }
        }
}

// ---------------- K4: scatter edges + GEMM layer 0 (independent; gemm tiles first) ----------------
__global__ __launch_bounds__(512) void scatgemm_kernel(
        const int* __restrict__ ei, const float* __restrict__ ew,
        const uint2* __restrict__ obnd, uint_t* __restrict__ cur,
        uint2* __restrict__ es, int E,
        const ushort_t* __restrict__ xb, const ushort_t* __restrict__ wall,
        ushort_t* __restrict__ Yall) {
    __shared__ __align__(16) ushort_t smem[24576];
    int bx = blockIdx.x;
    if (bx < 200) {
        gemm_body(bx, xb, wall, Yall, smem);
        return;
    }
    int e = (bx - 200) * 512 + threadIdx.x;
    if (e < E) {
        int src = ei[e];
        int dst = ei[E + e];
        float w = ew[e];
        if (w > 0.0f) {
            uint_t old = atomicAdd(&cur[dst], 1u);
            es[obnd[dst].x + (old & 0xffffu)] = make_uint2((uint_t)src, __float_as_uint(w));
        } else if (w < 0.0f) {
            uint_t old = atomicAdd(&cur[dst], 0x10000u);
            es[obnd[dst].y + (old >> 16)] = make_uint2((uint_t)src, __float_as_uint(-w));
        }
    }
}

// ---------------- standalone GEMM kernel (layers 1,2) ----------------
__global__ __launch_bounds__(512) void gemm_kernel(const ushort_t* __restrict__ A,
                                                   const ushort_t* __restrict__ Bw,
                                                   ushort_t* __restrict__ Y) {
    __shared__ __align__(16) ushort_t smem[24576];
    gemm_body(blockIdx.x, A, Bw, Y, smem);
}

// ---------------- aggregate projected rows + combine (R1-proven) ----------------
template <bool LEAKY>
__global__ __launch_bounds__(256) void agg_kernel(
        const ushort_t* __restrict__ Y,      // [12800 x 512]: Yp | Yn | Zp | Zn
        const uint2* __restrict__ obnd,
        const uint2* __restrict__ es,
        const float* __restrict__ bp, const float* __restrict__ bn,
        ushort_t* __restrict__ outp) {       // [12800 x 256]
    int lane = threadIdx.x & 63;
    int wv   = threadIdx.x >> 6;
    int n = blockIdx.x * 4 + wv;
    int c0 = lane * 2;                       // 2 cols per lane, 0..127
    uint2 ob = obnd[n];
    uint_t off = ob.x, mid = ob.y, end = obnd[n + 1].x;

    float accp[2] = {0.f, 0.f};
    float accn[2] = {0.f, 0.f};

#pragma unroll 1
    for (int phase = 0; phase < 2; ++phase) {
        uint_t lo = phase ? mid : off;
        uint_t hi = phase ? end : mid;
        float* acc = phase ? accn : accp;
        const ushort_t* Yb = Y + (phase ? 128 : 0) + c0;
#pragma unroll 1
        for (uint_t base = lo; base < hi; base += 64) {
            int cnt = (int)min(64u, hi - base);
            uint2 rec = es[base + (uint_t)min(lane, cnt - 1)];
            int i = 0;
#pragma unroll 1
            for (; i + 8 <= cnt; i += 8) {
                int s[8]; float w[8]; uint_t u[8];
#pragma unroll
                for (int j = 0; j < 8; ++j) {
                    s[j] = __shfl((int)rec.x, i + j);
                    w[j] = __uint_as_float((uint_t)__shfl((int)rec.y, i + j));
                }
#pragma unroll
                for (int j = 0; j < 8; ++j) u[j] = *(const uint_t*)&Yb[(size_t)s[j] * 512];
#pragma unroll
                for (int j = 0; j < 8; ++j) {
                    acc[0] = fmaf(w[j], bf2f((ushort_t)(u[j] & 0xffffu)), acc[0]);
                    acc[1] = fmaf(w[j], bf2f((ushort_t)(u[j] >> 16)), acc[1]);
                }
            }
#pragma unroll 1
            for (; i < cnt; ++i) {
                int s = __shfl((int)rec.x, i);
                float w = __uint_as_float((uint_t)__shfl((int)rec.y, i));
                uint_t u = *(const uint_t*)&Yb[(size_t)s * 512];
                acc[0] = fmaf(w, bf2f((ushort_t)(u & 0xffffu)), acc[0]);
                acc[1] = fmaf(w, bf2f((ushort_t)(u >> 16)), acc[1]);
            }
        }
    }

    float dp = fmaxf((float)(mid - off), 1.0f);
    float dn = fmaxf((float)(end - mid), 1.0f);
    float rp = 1.0f / dp, rn = 1.0f / dn;
    uint_t zp = *(const uint_t*)&Y[(size_t)n * 512 + 256 + c0];
    uint_t zn = *(const uint_t*)&Y[(size_t)n * 512 + 384 + c0];
    float vp0 = fmaf(accp[0], rp, bf2f((ushort_t)(zp & 0xffffu)) + bp[c0]);
    float vp1 = fmaf(accp[1], rp, bf2f((ushort_t)(zp >> 16))     + bp[c0 + 1]);
    float vn0 = fmaf(accn[0], rn, bf2f((ushort_t)(zn & 0xffffu)) + bn[c0]);
    float vn1 = fmaf(accn[1], rn, bf2f((ushort_t)(zn >> 16))     + bn[c0 + 1]);
    if (LEAKY) {
        vp0 = (vp0 > 0.0f) ? vp0 : 0.01f * vp0;
        vp1 = (vp1 > 0.0f) ? vp1 : 0.01f * vp1;
        vn0 = (vn0 > 0.0f) ? vn0 : 0.01f * vn0;
        vn1 = (vn1 > 0.0f) ? vn1 : 0.01f * vn1;
    }
    uint_t op = (uint_t)f2bf(vp0) | ((uint_t)f2bf(vp1) << 16);
    uint_t on = (uint_t)f2bf(vn0) | ((uint_t)f2bf(vn1) << 16);
    *(uint_t*)&outp[(size_t)n * 256 + c0]       = op;
    *(uint_t*)&outp[(size_t)n * 256 + 128 + c0] = on;
}

// ---------------- readout via MFMA, split-K partials (no atomics) ----------------
__global__ __launch_bounds__(256) void readout_mfma(
        const ushort_t* __restrict__ h, const float* __restrict__ Wr,
        float* __restrict__ partial) {
    __shared__ __align__(16) ushort_t As[64 * 32];
    __shared__ __align__(16) ushort_t Bs[64 * 32];
    int nBase  = blockIdx.x * 64;
    int kStart = blockIdx.y * 800;
    int tid  = threadIdx.x;
    int lane = tid & 63;
    int wv   = tid >> 6;
    int r    = lane & 15;
    int quad = lane >> 4;

    f32x4 acc[4];
#pragma unroll
    for (int j = 0; j < 4; ++j) acc[j] = (f32x4){0.f, 0.f, 0.f, 0.f};

    for (int kt = 0; kt < 25; ++kt) {
        int kBase = kStart + kt * 32;
        int lin = tid * 8;
        int row = lin >> 5, col = lin & 31;
        *(uint4*)&As[lin] = *(const uint4*)&h[(size_t)row * KREAD + kBase + col];
        {
            const float* wp = &Wr[(size_t)(nBase + row) * KREAD + kBase + col];
            float4 f0 = *(const float4*)&wp[0];
            float4 f1 = *(const float4*)&wp[4];
            ushort4 b0, b1;
            b0.x = f2bf(f0.x); b0.y = f2bf(f0.y); b0.z = f2bf(f0.z); b0.w = f2bf(f0.w);
            b1.x = f2bf(f1.x); b1.y = f2bf(f1.y); b1.z = f2bf(f1.z); b1.w = f2bf(f1.w);
            *(ushort4*)&Bs[lin]     = b0;
            *(ushort4*)&Bs[lin + 4] = b1;
        }
        __syncthreads();
        bf16x8 a = *(const bf16x8*)&As[(wv * 16 + r) * 32 + quad * 8];
#pragma unroll
        for (int j = 0; j < 4; ++j) {
            bf16x8 b = *(const bf16x8*)&Bs[(j * 16 + r) * 32 + quad * 8];
            acc[j] = __builtin_amdgcn_mfma_f32_16x16x32_bf16(a, b, acc[j], 0, 0, 0);
        }
        __syncthreads();
    }
    float* out = partial + (size_t)blockIdx.y * (64 * HID);
#pragma unroll
    for (int j = 0; j < 4; ++j) {
        int c = nBase + j * 16 + r;
#pragma unroll
        for (int reg = 0; reg < 4; ++reg) {
            int g = wv * 16 + quad * 4 + reg;
            out[g * HID + c] = acc[j][reg];
        }
    }
}

// ---------------- final: fold 64 partials, dot with Wl ----------------
__global__ void final_kernel(const float* __restrict__ partial, const float* __restrict__ br,
                             const float* __restrict__ Wl, const float* __restrict__ bl,
                             float* __restrict__ out) {
    int g = blockIdx.x;
    int c = threadIdx.x;   // 256
    float s = 0.0f;
#pragma unroll 4
    for (int k = 0; k < 64; ++k) s += partial[(size_t)k * (64 * HID) + g * HID + c];
    float v = (s + br[c]) * Wl[c];
#pragma unroll
    for (int d = 32; d > 0; d >>= 1) v += __shfl_down(v, d);
    __shared__ float sh[4];
    if ((c & 63) == 0) sh[c >> 6] = v;
    __syncthreads();
    if (c == 0) out[g] = sh[0] + sh[1] + sh[2] + sh[3] + bl[0];
}

// ---------------- launch ----------------
extern "C" void kernel_launch(void* const* d_in, const int* in_sizes, int n_in,
                              void* d_out, int out_size, void* d_ws, size_t ws_size,
                              hipStream_t stream) {
    const float* x  = (const float*)d_in[0];
    const int*   ei = (const int*)d_in[1];
    const float* ew = (const float*)d_in[2];
    const float* Wp0 = (const float*)d_in[4];
    const float* bp0 = (const float*)d_in[5];
    const float* Wn0 = (const float*)d_in[6];
    const float* bn0 = (const float*)d_in[7];
    const float* Wp1 = (const float*)d_in[8];
    const float* bp1 = (const float*)d_in[9];
    const float* Wn1 = (const float*)d_in[10];
    const float* bn1 = (const float*)d_in[11];
    const float* Wp2 = (const float*)d_in[12];
    const float* bp2 = (const float*)d_in[13];
    const float* Wn2 = (const float*)d_in[14];
    const float* bn2 = (const float*)d_in[15];
    const float* Wr  = (const float*)d_in[16];
    const float* br  = (const float*)d_in[17];
    const float* Wl  = (const float*)d_in[18];
    const float* bl  = (const float*)d_in[19];
    const int E = in_sizes[1] / 2;   // 409600

    // ---- workspace layout (bytes) ----
    char* ws = (char*)d_ws;
    float*    partial = (float*)(ws);                   // 4,194,304
    uint_t*   cnt     = (uint_t*)(ws + 4194304);        // 51,200   (cnt+cur adjacent)
    uint_t*   cur     = (uint_t*)(ws + 4245504);        // 51,200
    uint2*    obnd    = (uint2*)(ws + 4296704);         // 12801*8 -> 4,399,168 (+pad)
    uint2*    es      = (uint2*)(ws + 4399168);         // E*8 = 3,276,800
    ushort_t* Yall    = (ushort_t*)(ws + 7675968);      // 12800*512*2 = 13,107,200
    ushort_t* hA      = (ushort_t*)(ws + 20783168);     // 6,553,600
    ushort_t* hB      = (ushort_t*)(ws + 27336768);     // 6,553,600
    ushort_t* wall    = (ushort_t*)(ws + 33890368);     // 3*512*256*2 = 786,432
    ushort_t* xb      = (ushort_t*)(ws + 34676800);     // 6,553,600 -> 41,230,400

    // K1: zero cnt/cur + weight cast/rearrange + x cast/pad
    hipLaunchKernelGGL(prep_kernel, dim3(512), dim3(256), 0, stream,
                       Wp0, Wn0, Wp1, Wn1, Wp2, Wn2, x, cnt, wall, xb);
    // K2: histogram
    hipLaunchKernelGGL(hist_kernel, dim3((E + 511) / 512), dim3(512), 0, stream, ei, ew, cnt, E);
    // K3: scan -> obnd
    hipLaunchKernelGGL(scan_kernel, dim3(1), dim3(1024), 0, stream, cnt, obnd, N_NODES);
    // K4: scatter + GEMM layer 0 (fused; gemm tiles = blocks 0..199)
    hipLaunchKernelGGL(scatgemm_kernel, dim3(200 + (E + 511) / 512), dim3(512), 0, stream,
                       ei, ew, obnd, cur, es, E, xb, wall, Yall);
    // layer 0 agg
    hipLaunchKernelGGL((agg_kernel<true>), dim3(N_NODES / 4), dim3(256), 0, stream,
                       Yall, obnd, es, bp0, bn0, hA);
    // layer 1
    hipLaunchKernelGGL(gemm_kernel, dim3(200), dim3(512), 0, stream, hA, wall + 131072, Yall);
    hipLaunchKernelGGL((agg_kernel<true>), dim3(N_NODES / 4), dim3(256), 0, stream,
                       Yall, obnd, es, bp1, bn1, hB);
    // layer 2
    hipLaunchKernelGGL(gemm_kernel, dim3(200), dim3(512), 0, stream, hB, wall + 262144, Yall);
    hipLaunchKernelGGL((agg_kernel<false>), dim3(N_NODES / 4), dim3(256), 0, stream,
                       Yall, obnd, es, bp2, bn2, hA);
    // readout + final
    hipLaunchKernelGGL(readout_mfma, dim3(4, 64), dim3(256), 0, stream, hA, Wr, partial);
    hipLaunchKernelGGL(final_kernel, dim3(NUM_GRAPHS), dim3(256), 0, stream,
                       partial, br, Wl, bl, (float*)d_out);
}